// Round 11
// baseline (1874.350 us; speedup 1.0000x reference)
//
#include <hip/hip_runtime.h>
#include <hip/hip_bf16.h>
#include <math.h>

// ============================================================================
// AuroraBlock round 11: fused 4-step kernel, 2 pos/wave, NO-LDS weight path.
//   - weights stream L2 -> VGPR directly (global_load_dwordx4, coalesced
//     16B/lane); packed stream order identical to rounds 7-10.
//   - NO barriers / staging / vmcnt in the main loop: waves fully independent
//     -> the 8 waves/CU desync and overlap LDS/MFMA/VALU pipes (rounds 8-10
//     showed barrier-lockstep serialized them: 33+39+43 ~= 110% additive).
//   - L2 floor: 2048 waves x 6MB = 12.3GB / 34.5TB/s ~= 356us; MFMA ~199us.
//   - everything else identical to round 8 (2 pos/wave, Wo folded per head,
//     r f32 in regs, candidate combine in-wave).
// ws (floats): [0..65535] mask | [65536..69631] sproj | [69632..81919] probs
//   [81920..81923] accum | shorts at float offset 131072:
//   Wstream(786432) PWa1(32768) PWd1(131072)
// d_out: [0..16777215] r_out, [16777216] routing_loss, [16777217] mean_k
// ============================================================================

#define NPOS 4096
#define R_ELEMS 16777216ull

typedef __attribute__((ext_vector_type(8))) short short8;
typedef __attribute__((ext_vector_type(4))) float f32x4;

#define MF(a, b, c) __builtin_amdgcn_mfma_f32_16x16x32_bf16(a, b, c, 0, 0, 0)

__device__ __forceinline__ short bf16rne(float f) {
  union { float f; unsigned u; } v; v.f = f;
  unsigned r = v.u + 0x7FFFu + ((v.u >> 16) & 1u);
  return (short)(r >> 16);
}

__device__ __forceinline__ short bf16c(float f) {
  __hip_bfloat16 h = __float2bfloat16(f);
  return *reinterpret_cast<short*>(&h);
}

__device__ __forceinline__ float fast_gelu(float x) {
  float x2 = x * x;
  float z = 0.7978845608028654f * x * (1.f + 0.044715f * x2);
  float e = __expf(2.f * z);  // tanh(z) = 1 - 2/(e^{2z}+1)
  float t = 1.f - 2.f * __builtin_amdgcn_rcpf(e + 1.f);
  return 0.5f * x * (1.f + t);
}

// ---- packing for difficulty/slot_mask (fragment-array layout) ----
__global__ void pack_weight(const float* __restrict__ W, short* __restrict__ P,
                            int K, int N) {
  int id = blockIdx.x * 256 + threadIdx.x;
  int KC = K >> 5, T = N >> 4;
  if (id >= T * KC * 64) return;
  int l = id & 63, kc = (id >> 6) % KC, t = id / (64 * KC);
  int g = l >> 4, n = l & 15;
  short8 o;
#pragma unroll
  for (int jj = 0; jj < 8; jj++) {
    int k = 32 * kc + 4 * g + (jj & 3) + 16 * (jj >> 2);
    o[jj] = bf16rne(W[(size_t)k * N + 16 * t + n]);
  }
  *(short8*)(P + (size_t)id * 8) = o;
}

// ---- pack reasoning weights, consumption order v2 (Wo interleaved/head) ----
// 1536 frags: [head 0..3]: q(32: tp*16+tt*8+kc), k(32), v(32),
//                          Wo-rows (32: ch*16 + tloc*2 + kcl)
//             FFN: per hc(32): Wf1 (16: tt*8+kc), Wf2 (16: t)
__global__ void pack_stream(const float* __restrict__ Wq, const float* __restrict__ Wk,
                            const float* __restrict__ Wv, const float* __restrict__ Wo,
                            const float* __restrict__ Wf1, const float* __restrict__ Wf2,
                            short* __restrict__ S) {
  int id = blockIdx.x * 256 + threadIdx.x;
  int f = id >> 6, lane = id & 63;
  if (f >= 1536) return;
  const float* W; int ldN, t, kc;
  if (f < 512) {
    int head = f >> 7, rem = f & 127;
    if (rem < 96) {
      int mat = rem / 32, r2 = rem % 32;
      t = 4 * head + (r2 >> 3);
      kc = r2 & 7; ldN = 256;
      W = (mat == 0) ? Wq : (mat == 1) ? Wk : Wv;
    } else {
      int r2 = rem - 96;             // 0..31
      int ch = r2 >> 4, floc = r2 & 15;
      t = ch * 8 + (floc >> 1);
      kc = 2 * head + (floc & 1);
      ldN = 256; W = Wo;
    }
  } else {
    int gg = f - 512, hc = gg / 32, r2 = gg % 32;
    if (r2 < 16) { W = Wf1; ldN = 1024; t = 2 * hc + (r2 >> 3); kc = r2 & 7; }
    else         { W = Wf2; ldN = 256;  t = r2 - 16;            kc = hc;    }
  }
  int g = lane >> 4, n = lane & 15;
  short8 o;
#pragma unroll
  for (int jj = 0; jj < 8; jj++) {
    int k = 32 * kc + 4 * g + (jj & 3) + 16 * (jj >> 2);
    o[jj] = bf16rne(W[(size_t)k * ldN + 16 * t + n]);
  }
  *(short8*)(S + (size_t)f * 512 + lane * 8) = o;
}

__device__ __forceinline__ short8 ldfrag(const short* __restrict__ P, int t, int kc,
                                         int KC, int lane) {
  return *(const short8*)(P + ((size_t)((t * KC + kc) * 64 + lane) << 3));
}

__global__ void init_accum_kernel(float* accum) {
  if (threadIdx.x < 4) accum[threadIdx.x] = 0.f;
}

__global__ void sproj_kernel(const float* __restrict__ s, const float* __restrict__ Ws,
                             float* __restrict__ sproj) {
  int p = blockIdx.x, tid = threadIdx.x;
  const float* row = s + (size_t)p * 1024;
  float sum = 0.f;
#pragma unroll
  for (int k0 = 0; k0 < 1024; k0 += 256) sum += row[k0 + tid] * Ws[k0 + tid];
#pragma unroll
  for (int m = 1; m < 64; m <<= 1) sum += __shfl_xor(sum, m, 64);
  __shared__ float red[4];
  if ((tid & 63) == 0) red[tid >> 6] = sum;
  __syncthreads();
  if (tid == 0) sproj[p] = red[0] + red[1] + red[2] + red[3];
}

__global__ void difficulty_mfma(const float* __restrict__ s, const short* __restrict__ PWd1,
                                const float* __restrict__ bd1, const float* __restrict__ Wd2,
                                const float* __restrict__ bd2, float* __restrict__ probsv,
                                float* __restrict__ accum) {
  int tid = threadIdx.x;
  int wave = tid >> 6, lane = tid & 63, n = lane & 15, g = lane >> 4;
  int p0 = (blockIdx.x * 4 + wave) * 16;
  const float* sg = s + (size_t)(p0 + n) * 1024;
  f32x4 ha[8];
  const f32x4 Z = {0.f, 0.f, 0.f, 0.f};
#pragma unroll
  for (int t = 0; t < 8; t++) ha[t] = Z;
  for (int kc = 0; kc < 32; kc++) {
    f32x4 x0 = *(const f32x4*)(sg + 32 * kc + 4 * g);
    f32x4 x1 = *(const f32x4*)(sg + 32 * kc + 16 + 4 * g);
    short8 sb;
#pragma unroll
    for (int c = 0; c < 4; c++) { sb[c] = bf16c(x0[c]); sb[c + 4] = bf16c(x1[c]); }
#pragma unroll
    for (int t = 0; t < 8; t++) ha[t] = MF(ldfrag(PWd1, t, kc, 32, lane), sb, ha[t]);
  }
  float v0 = 0.f, v1 = 0.f, v2 = 0.f;
#pragma unroll
  for (int t = 0; t < 8; t++)
#pragma unroll
    for (int c = 0; c < 4; c++) {
      int hid = 16 * t + 4 * g + c;
      float u = fmaxf(ha[t][c] + bd1[hid], 0.f);
      v0 += u * Wd2[hid * 3 + 0];
      v1 += u * Wd2[hid * 3 + 1];
      v2 += u * Wd2[hid * 3 + 2];
    }
  v0 += __shfl_xor(v0, 16, 64); v0 += __shfl_xor(v0, 32, 64);
  v1 += __shfl_xor(v1, 16, 64); v1 += __shfl_xor(v1, 32, 64);
  v2 += __shfl_xor(v2, 16, 64); v2 += __shfl_xor(v2, 32, 64);
  if (g == 0) {
    float l0 = v0 + bd2[0], l1 = v1 + bd2[1], l2 = v2 + bd2[2];
    float mx = fmaxf(l0, fmaxf(l1, l2));
    float e0 = __expf(l0 - mx), e1 = __expf(l1 - mx), e2 = __expf(l2 - mx);
    float inv = 1.f / (e0 + e1 + e2);
    float p0v = e0 * inv, p1v = e1 * inv, p2v = e2 * inv;
    int p = p0 + n;
    probsv[p * 3 + 0] = p0v; probsv[p * 3 + 1] = p1v; probsv[p * 3 + 2] = p2v;
    atomicAdd(accum + 0, p0v);
    atomicAdd(accum + 1, p1v);
    atomicAdd(accum + 2, p2v);
    atomicAdd(accum + 3, p0v * 1.f + p1v * 2.f + p2v * 4.f);
  }
}

__global__ void slot_mask_mfma(const float* __restrict__ r, const short* __restrict__ PWa1,
                               const float* __restrict__ ba1, const float* __restrict__ Wa2,
                               const float* __restrict__ ba2, const float* __restrict__ sproj,
                               float* __restrict__ mask) {
  int tid = threadIdx.x;
  int wave = tid >> 6, lane = tid & 63, n = lane & 15, g = lane >> 4;
  int p = blockIdx.x * 4 + wave;
  const float* rsg = r + (size_t)p * 4096 + n * 256;
  short8 rb[8];
#pragma unroll
  for (int kc = 0; kc < 8; kc++) {
    f32x4 x0 = *(const f32x4*)(rsg + 32 * kc + 4 * g);
    f32x4 x1 = *(const f32x4*)(rsg + 32 * kc + 16 + 4 * g);
    short8 o;
#pragma unroll
    for (int c = 0; c < 4; c++) { o[c] = bf16c(x0[c]); o[c + 4] = bf16c(x1[c]); }
    rb[kc] = o;
  }
  f32x4 ha[8];
  const f32x4 Z = {0.f, 0.f, 0.f, 0.f};
#pragma unroll
  for (int t = 0; t < 8; t++) ha[t] = Z;
#pragma unroll
  for (int kc = 0; kc < 8; kc++)
#pragma unroll
    for (int t = 0; t < 8; t++) ha[t] = MF(ldfrag(PWa1, t, kc, 8, lane), rb[kc], ha[t]);
  float v = 0.f;
#pragma unroll
  for (int t = 0; t < 8; t++)
#pragma unroll
    for (int c = 0; c < 4; c++) {
      int hid = 16 * t + 4 * g + c;
      v += fmaxf(ha[t][c] + ba1[hid], 0.f) * Wa2[hid];
    }
  v += __shfl_xor(v, 16, 64);
  v += __shfl_xor(v, 32, 64);
  if (g == 0) mask[p * 16 + n] = 1.f / (1.f + __expf(-(v + ba2[0] + sproj[p])));
}

// ====== fused 4-step reasoning kernel, 2 pos/wave, L2->VGPR weights ======
__global__ __launch_bounds__(256, 2) void reason_all(
    const float* __restrict__ r_src, const float* __restrict__ maskg,
    const float* __restrict__ probsv, float* __restrict__ outp,
    const short* __restrict__ Wstream,
    const float* __restrict__ ln1s, const float* __restrict__ ln1b,
    const float* __restrict__ ln2s, const float* __restrict__ ln2b,
    const float* __restrict__ bf1g, const float* __restrict__ bf2g) {
  __shared__ __align__(16) float P_ln1s[256], P_ln1b[256], P_ln2s[256], P_ln2b[256];
  __shared__ __align__(16) float P_bf1[1024], P_bf2[256];
  const int tid = threadIdx.x;
  P_ln1s[tid] = ln1s[tid]; P_ln1b[tid] = ln1b[tid];
  P_ln2s[tid] = ln2s[tid]; P_ln2b[tid] = ln2b[tid];
  P_bf2[tid] = bf2g[tid];
  for (int i = tid; i < 1024; i += 256) P_bf1[i] = bf1g[i];
  __syncthreads();  // params ready; no barriers after this point

  const int wave = tid >> 6, lane = tid & 63;
  const int n = lane & 15, g = lane >> 4;
  const int pA = blockIdx.x * 8 + wave * 2, pB = pA + 1;
  const size_t baseA = (size_t)pA * 4096, baseB = (size_t)pB * 4096;
  const f32x4 Z = {0.f, 0.f, 0.f, 0.f};

  // fragment fetch: absolute frag index into the packed stream (L2-resident)
  const short* const Wl = Wstream + lane * 8;
#define GF(fi) (*(const short8*)(Wl + (size_t)(fi) * 512))

  // ---- r for both positions -> regs ----
  f32x4 rA0[8], rA1[8], rB0[8], rB1[8];
  {
    const float* ra = r_src + baseA + n * 256;
    const float* rb = r_src + baseB + n * 256;
#pragma unroll
    for (int kc = 0; kc < 8; kc++) {
      rA0[kc] = *(const f32x4*)(ra + 32 * kc + 4 * g);
      rA1[kc] = *(const f32x4*)(ra + 32 * kc + 16 + 4 * g);
      rB0[kc] = *(const f32x4*)(rb + 32 * kc + 4 * g);
      rB1[kc] = *(const f32x4*)(rb + 32 * kc + 16 + 4 * g);
    }
  }
  const float maskA = maskg[pA * 16 + n];
  const float maskB = maskg[pB * 16 + n];

  short8 hA[8], hB[8];
  auto do_ln = [&](const f32x4* r0, const f32x4* r1, const float* sc,
                   const float* bi, short8* h) {
    float sum = 0.f, sq = 0.f;
#pragma unroll
    for (int kc = 0; kc < 8; kc++)
#pragma unroll
      for (int c = 0; c < 4; c++) {
        sum += r0[kc][c] + r1[kc][c];
        sq += r0[kc][c] * r0[kc][c] + r1[kc][c] * r1[kc][c];
      }
    sum += __shfl_xor(sum, 16, 64); sq += __shfl_xor(sq, 16, 64);
    sum += __shfl_xor(sum, 32, 64); sq += __shfl_xor(sq, 32, 64);
    float mu = sum * (1.f / 256.f);
    float inv = rsqrtf(sq * (1.f / 256.f) - mu * mu + 1e-5f);
#pragma unroll
    for (int kc = 0; kc < 8; kc++) {
      f32x4 s0 = *(const f32x4*)&sc[32 * kc + 4 * g];
      f32x4 b0 = *(const f32x4*)&bi[32 * kc + 4 * g];
      f32x4 s1 = *(const f32x4*)&sc[32 * kc + 16 + 4 * g];
      f32x4 b1 = *(const f32x4*)&bi[32 * kc + 16 + 4 * g];
      short8 hh;
#pragma unroll
      for (int c = 0; c < 4; c++) {
        hh[c]     = bf16c((r0[kc][c] - mu) * inv * s0[c] + b0[c]);
        hh[c + 4] = bf16c((r1[kc][c] - mu) * inv * s1[c] + b1[c]);
      }
      h[kc] = hh;
    }
  };

#pragma unroll 1
  for (int sidx = 0; sidx < 4; ++sidx) {
    // ================= attention (Wo folded per head) =================
    do_ln(rA0, rA1, P_ln1s, P_ln1b, hA);
    do_ln(rB0, rB1, P_ln1s, P_ln1b, hB);

#pragma unroll 1
    for (int hh = 0; hh < 4; ++hh) {
      const int hb = hh * 128;
      short8 qbA[2], qbB[2], kbA[2], kbB[2];
      // ---- Q: frags hb + tp*16 + {kc, 8+kc} ----
#pragma unroll
      for (int tp = 0; tp < 2; ++tp) {
        f32x4 a0A = Z, a1A = Z, a0B = Z, a1B = Z;
        __builtin_amdgcn_s_setprio(1);
#pragma unroll
        for (int kc = 0; kc < 8; kc++) {
          short8 fr = GF(hb + tp * 16 + kc);
          a0A = MF(fr, hA[kc], a0A); a0B = MF(fr, hB[kc], a0B);
        }
#pragma unroll
        for (int kc = 0; kc < 8; kc++) {
          short8 fr = GF(hb + tp * 16 + 8 + kc);
          a1A = MF(fr, hA[kc], a1A); a1B = MF(fr, hB[kc], a1B);
        }
        __builtin_amdgcn_s_setprio(0);
        short8 xA, xB;
#pragma unroll
        for (int jj = 0; jj < 8; jj++) {
          xA[jj] = bf16c(jj < 4 ? a0A[jj & 3] : a1A[jj & 3]);
          xB[jj] = bf16c(jj < 4 ? a0B[jj & 3] : a1B[jj & 3]);
        }
        qbA[tp] = xA; qbB[tp] = xB;
      }
      // ---- K: frags hb + 32 + tp*16 + {kc, 8+kc} ----
#pragma unroll
      for (int tp = 0; tp < 2; ++tp) {
        f32x4 a0A = Z, a1A = Z, a0B = Z, a1B = Z;
        __builtin_amdgcn_s_setprio(1);
#pragma unroll
        for (int kc = 0; kc < 8; kc++) {
          short8 fr = GF(hb + 32 + tp * 16 + kc);
          a0A = MF(fr, hA[kc], a0A); a0B = MF(fr, hB[kc], a0B);
        }
#pragma unroll
        for (int kc = 0; kc < 8; kc++) {
          short8 fr = GF(hb + 32 + tp * 16 + 8 + kc);
          a1A = MF(fr, hA[kc], a1A); a1B = MF(fr, hB[kc], a1B);
        }
        __builtin_amdgcn_s_setprio(0);
        short8 xA, xB;
#pragma unroll
        for (int jj = 0; jj < 8; jj++) {
          xA[jj] = bf16c(jj < 4 ? a0A[jj & 3] : a1A[jj & 3]);
          xB[jj] = bf16c(jj < 4 ? a0B[jj & 3] : a1B[jj & 3]);
        }
        kbA[tp] = xA; kbB[tp] = xB;
      }
      // ---- scores + softmax per pos ----
      short8 pbA, pbB;
      {
        f32x4 sc1 = Z;
        sc1 = MF(kbA[0], qbA[0], sc1);
        sc1 = MF(kbA[1], qbA[1], sc1);
#pragma unroll
        for (int c = 0; c < 4; c++) sc1[c] *= 0.125f;
        float mx = fmaxf(fmaxf(sc1[0], sc1[1]), fmaxf(sc1[2], sc1[3]));
        mx = fmaxf(mx, __shfl_xor(mx, 16, 64));
        mx = fmaxf(mx, __shfl_xor(mx, 32, 64));
        float e0 = __expf(sc1[0] - mx), e1 = __expf(sc1[1] - mx);
        float e2 = __expf(sc1[2] - mx), e3 = __expf(sc1[3] - mx);
        float sm = e0 + e1 + e2 + e3;
        sm += __shfl_xor(sm, 16, 64);
        sm += __shfl_xor(sm, 32, 64);
        float isv = __builtin_amdgcn_rcpf(sm);
        pbA[0] = bf16c(e0 * isv); pbA[1] = bf16c(e1 * isv);
        pbA[2] = bf16c(e2 * isv); pbA[3] = bf16c(e3 * isv);
        pbA[4] = 0; pbA[5] = 0; pbA[6] = 0; pbA[7] = 0;
      }
      {
        f32x4 sc1 = Z;
        sc1 = MF(kbB[0], qbB[0], sc1);
        sc1 = MF(kbB[1], qbB[1], sc1);
#pragma unroll
        for (int c = 0; c < 4; c++) sc1[c] *= 0.125f;
        float mx = fmaxf(fmaxf(sc1[0], sc1[1]), fmaxf(sc1[2], sc1[3]));
        mx = fmaxf(mx, __shfl_xor(mx, 16, 64));
        mx = fmaxf(mx, __shfl_xor(mx, 32, 64));
        float e0 = __expf(sc1[0] - mx), e1 = __expf(sc1[1] - mx);
        float e2 = __expf(sc1[2] - mx), e3 = __expf(sc1[3] - mx);
        float sm = e0 + e1 + e2 + e3;
        sm += __shfl_xor(sm, 16, 64);
        sm += __shfl_xor(sm, 32, 64);
        float isv = __builtin_amdgcn_rcpf(sm);
        pbB[0] = bf16c(e0 * isv); pbB[1] = bf16c(e1 * isv);
        pbB[2] = bf16c(e2 * isv); pbB[3] = bf16c(e3 * isv);
        pbB[4] = 0; pbB[5] = 0; pbB[6] = 0; pbB[7] = 0;
      }
      // ---- V + PV -> o-slices (mask folded): frags hb + 64 + ... ----
      short8 osA[2], osB[2];
#pragma unroll
      for (int tp = 0; tp < 2; ++tp) {
        f32x4 v0A = Z, v1A = Z, v0B = Z, v1B = Z;
        __builtin_amdgcn_s_setprio(1);
#pragma unroll
        for (int kc = 0; kc < 8; kc++) {
          short8 fr = GF(hb + 64 + tp * 16 + kc);
          v0A = MF(hA[kc], fr, v0A); v0B = MF(hB[kc], fr, v0B);
        }
#pragma unroll
        for (int kc = 0; kc < 8; kc++) {
          short8 fr = GF(hb + 64 + tp * 16 + 8 + kc);
          v1A = MF(hA[kc], fr, v1A); v1B = MF(hB[kc], fr, v1B);
        }
        __builtin_amdgcn_s_setprio(0);
        short8 vb0A, vb1A, vb0B, vb1B;
#pragma unroll
        for (int c = 0; c < 4; c++) {
          vb0A[c] = bf16c(v0A[c]); vb1A[c] = bf16c(v1A[c]);
          vb0B[c] = bf16c(v0B[c]); vb1B[c] = bf16c(v1B[c]);
          vb0A[c + 4] = 0; vb1A[c + 4] = 0; vb0B[c + 4] = 0; vb1B[c + 4] = 0;
        }
        f32x4 oh0A = MF(vb0A, pbA, Z), oh1A = MF(vb1A, pbA, Z);
        f32x4 oh0B = MF(vb0B, pbB, Z), oh1B = MF(vb1B, pbB, Z);
        short8 yA, yB;
#pragma unroll
        for (int jj = 0; jj < 8; jj++) {
          yA[jj] = bf16c(maskA * (jj < 4 ? oh0A[jj & 3] : oh1A[jj & 3]));
          yB[jj] = bf16c(maskB * (jj < 4 ? oh0B[jj & 3] : oh1B[jj & 3]));
        }
        osA[tp] = yA; osB[tp] = yB;
      }
      // ---- Wo fold: frags hb + 96 + ch*16 + 2*tloc + {0,1} ----
      __builtin_amdgcn_s_setprio(1);
#pragma unroll
      for (int ch = 0; ch < 2; ++ch) {
#pragma unroll
        for (int tloc = 0; tloc < 8; ++tloc) {
          short8 f0 = GF(hb + 96 + ch * 16 + 2 * tloc);
          short8 f1 = GF(hb + 96 + ch * 16 + 2 * tloc + 1);
          int kk = ch * 4 + (tloc >> 1);
          if ((tloc & 1) == 0) {
            rA0[kk] = MF(f0, osA[0], rA0[kk]); rA0[kk] = MF(f1, osA[1], rA0[kk]);
            rB0[kk] = MF(f0, osB[0], rB0[kk]); rB0[kk] = MF(f1, osB[1], rB0[kk]);
          } else {
            rA1[kk] = MF(f0, osA[0], rA1[kk]); rA1[kk] = MF(f1, osA[1], rA1[kk]);
            rB1[kk] = MF(f0, osB[0], rB1[kk]); rB1[kk] = MF(f1, osB[1], rB1[kk]);
          }
        }
      }
      __builtin_amdgcn_s_setprio(0);
    }

    // ================= FFN =================
    do_ln(rA0, rA1, P_ln2s, P_ln2b, hA);
    do_ln(rB0, rB1, P_ln2s, P_ln2b, hB);
#pragma unroll 1
    for (int hc = 0; hc < 32; hc++) {
      const int fb = 512 + hc * 32;
      f32x4 t0A = Z, t1A = Z, t0B = Z, t1B = Z;
      __builtin_amdgcn_s_setprio(1);
#pragma unroll
      for (int kc = 0; kc < 8; kc++) {
        short8 fr = GF(fb + kc);
        t0A = MF(fr, hA[kc], t0A); t0B = MF(fr, hB[kc], t0B);
      }
#pragma unroll
      for (int kc = 0; kc < 8; kc++) {
        short8 fr = GF(fb + 8 + kc);
        t1A = MF(fr, hA[kc], t1A); t1B = MF(fr, hB[kc], t1B);
      }
      __builtin_amdgcn_s_setprio(0);
      f32x4 u0 = *(const f32x4*)&P_bf1[32 * hc + 4 * g];
      f32x4 u1 = *(const f32x4*)&P_bf1[32 * hc + 16 + 4 * g];
      short8 hbbA, hbbB;
#pragma unroll
      for (int c = 0; c < 4; c++) {
        hbbA[c]     = bf16c(maskA * fast_gelu(t0A[c] + u0[c]));
        hbbA[c + 4] = bf16c(maskA * fast_gelu(t1A[c] + u1[c]));
        hbbB[c]     = bf16c(maskB * fast_gelu(t0B[c] + u0[c]));
        hbbB[c + 4] = bf16c(maskB * fast_gelu(t1B[c] + u1[c]));
      }
      __builtin_amdgcn_s_setprio(1);
#pragma unroll
      for (int tt = 0; tt < 8; tt++) {
        short8 f0 = GF(fb + 16 + 2 * tt);
        short8 f1 = GF(fb + 16 + 2 * tt + 1);
        rA0[tt] = MF(f0, hbbA, rA0[tt]); rB0[tt] = MF(f0, hbbB, rB0[tt]);
        rA1[tt] = MF(f1, hbbA, rA1[tt]); rB1[tt] = MF(f1, hbbB, rB1[tt]);
      }
      __builtin_amdgcn_s_setprio(0);
    }
    // ---- FFN bias residual ----
#pragma unroll
    for (int kc = 0; kc < 8; kc++) {
      f32x4 b0 = *(const f32x4*)&P_bf2[32 * kc + 4 * g];
      f32x4 b1 = *(const f32x4*)&P_bf2[32 * kc + 16 + 4 * g];
#pragma unroll
      for (int c = 0; c < 4; c++) {
        rA0[kc][c] += maskA * b0[c]; rA1[kc][c] += maskA * b1[c];
        rB0[kc][c] += maskB * b0[c]; rB1[kc][c] += maskB * b1[c];
      }
    }

    // ---- candidate combine ----
    if (sidx == 0) {
      float wa = probsv[pA * 3 + 0], wb = probsv[pB * 3 + 0];
      float* oa = outp + baseA + n * 256;
      float* ob2 = outp + baseB + n * 256;
#pragma unroll
      for (int kc = 0; kc < 8; kc++) {
        f32x4 xa0, xa1, xb0, xb1;
#pragma unroll
        for (int c = 0; c < 4; c++) {
          xa0[c] = wa * rA0[kc][c]; xa1[c] = wa * rA1[kc][c];
          xb0[c] = wb * rB0[kc][c]; xb1[c] = wb * rB1[kc][c];
        }
        *(f32x4*)(oa + 32 * kc + 4 * g) = xa0;
        *(f32x4*)(oa + 32 * kc + 16 + 4 * g) = xa1;
        *(f32x4*)(ob2 + 32 * kc + 4 * g) = xb0;
        *(f32x4*)(ob2 + 32 * kc + 16 + 4 * g) = xb1;
      }
    } else if (sidx == 1 || sidx == 3) {
      int ci = (sidx == 1) ? 1 : 2;
      float wa = probsv[pA * 3 + ci], wb = probsv[pB * 3 + ci];
      float* oa = outp + baseA + n * 256;
      float* ob2 = outp + baseB + n * 256;
#pragma unroll
      for (int kc = 0; kc < 8; kc++) {
        f32x4 xa0 = *(f32x4*)(oa + 32 * kc + 4 * g);
        f32x4 xa1 = *(f32x4*)(oa + 32 * kc + 16 + 4 * g);
        f32x4 xb0 = *(f32x4*)(ob2 + 32 * kc + 4 * g);
        f32x4 xb1 = *(f32x4*)(ob2 + 32 * kc + 16 + 4 * g);
#pragma unroll
        for (int c = 0; c < 4; c++) {
          xa0[c] += wa * rA0[kc][c]; xa1[c] += wa * rA1[kc][c];
          xb0[c] += wb * rB0[kc][c]; xb1[c] += wb * rB1[kc][c];
        }
        *(f32x4*)(oa + 32 * kc + 4 * g) = xa0;
        *(f32x4*)(oa + 32 * kc + 16 + 4 * g) = xa1;
        *(f32x4*)(ob2 + 32 * kc + 4 * g) = xb0;
        *(f32x4*)(ob2 + 32 * kc + 16 + 4 * g) = xb1;
      }
    }
  }
}

__global__ void finalize_kernel(const float* __restrict__ accum, float* __restrict__ dst) {
  const float inv = 1.f / 4096.f;
  float m0 = accum[0] * inv, m1 = accum[1] * inv, m2 = accum[2] * inv;
  const float u = 1.f / 3.f;
  float d0 = m0 - u, d1 = m1 - u, d2 = m2 - u;
  dst[0] = (d0 * d0 + d1 * d1 + d2 * d2) * (1.f / 3.f);
  dst[1] = accum[3] * inv;
}

extern "C" void kernel_launch(void* const* d_in, const int* in_sizes, int n_in,
                              void* d_out, int out_size, void* d_ws, size_t ws_size,
                              hipStream_t stream) {
  const float* s    = (const float*)d_in[0];
  const float* r    = (const float*)d_in[1];
  const float* Wd1  = (const float*)d_in[2];
  const float* bd1  = (const float*)d_in[3];
  const float* Wd2  = (const float*)d_in[4];
  const float* bd2  = (const float*)d_in[5];
  const float* Wa1  = (const float*)d_in[6];
  const float* ba1  = (const float*)d_in[7];
  const float* Wa2  = (const float*)d_in[8];
  const float* ba2  = (const float*)d_in[9];
  const float* Wsp  = (const float*)d_in[10];
  const float* ln1s = (const float*)d_in[11];
  const float* ln1b = (const float*)d_in[12];
  const float* Wq   = (const float*)d_in[13];
  const float* Wk   = (const float*)d_in[14];
  const float* Wv   = (const float*)d_in[15];
  const float* Wo   = (const float*)d_in[16];
  const float* ln2s = (const float*)d_in[17];
  const float* ln2b = (const float*)d_in[18];
  const float* Wf1  = (const float*)d_in[19];
  const float* bf1  = (const float*)d_in[20];
  const float* Wf2  = (const float*)d_in[21];
  const float* bf2  = (const float*)d_in[22];

  float* out = (float*)d_out;
  float* wsf = (float*)d_ws;
  float* mask   = wsf;
  float* sproj  = wsf + 65536;
  float* probsv = wsf + 65536 + 4096;
  float* accum  = wsf + 65536 + 4096 + 12288;
  short* pk     = (short*)(wsf + 131072);
  short* Wstream = pk;             // 786432 shorts (1536 x 1KB frags)
  short* PWa1    = pk + 786432;    // 32768
  short* PWd1    = pk + 819200;    // 131072

  pack_stream<<<384, 256, 0, stream>>>(Wq, Wk, Wv, Wo, Wf1, Wf2, Wstream);
  pack_weight<<<16, 256, 0, stream>>>(Wa1, PWa1, 256, 128);
  pack_weight<<<64, 256, 0, stream>>>(Wd1, PWd1, 1024, 128);

  init_accum_kernel<<<1, 64, 0, stream>>>(accum);
  sproj_kernel<<<NPOS, 256, 0, stream>>>(s, Wsp, sproj);
  difficulty_mfma<<<64, 256, 0, stream>>>(s, PWd1, bd1, Wd2, bd2, probsv, accum);
  slot_mask_mfma<<<NPOS / 4, 256, 0, stream>>>(r, PWa1, ba1, Wa2, ba2, sproj, mask);

  reason_all<<<NPOS / 8, 256, 0, stream>>>(r, mask, probsv, out, Wstream,
                                           ln1s, ln1b, ln2s, ln2b, bf1, bf2);

  finalize_kernel<<<1, 1, 0, stream>>>(accum, out + R_ELEMS);
}

// Round 12
// 654.092 us; speedup vs baseline: 2.8656x; 2.8656x over previous
//
#include <hip/hip_runtime.h>
#include <hip/hip_bf16.h>
#include <math.h>

// ============================================================================
// AuroraBlock round 12: round-8 champion, cleaned (final structure).
//   - 2 pos/wave, paired 16KB chunks, ring-4 LDS (64KB), vmcnt(0)+s_barrier
//     per paired boundary, Wo folded per head, r f32 in AGPRs across 4 steps.
//   - REMOVED vs round 10: cross-block stagger (proven null, r10) and
//     s_setprio (m190: hurts barrier-lockstep kernels).
//   - Design-space map (r9/r10/r11 falsifications): shared LDS staging is
//     mandatory; staging => barrier lockstep; regs exhausted (128V+128A).
// ws (floats): [0..65535] mask | [65536..69631] sproj | [69632..81919] probs
//   [81920..81923] accum | shorts at float offset 131072:
//   Wstream(786432) PWa1(32768) PWd1(131072)
// d_out: [0..16777215] r_out, [16777216] routing_loss, [16777217] mean_k
// ============================================================================

#define NPOS 4096
#define R_ELEMS 16777216ull
#define NCHUNK 384  // 16KB chunks total (96/step * 4 steps)

typedef __attribute__((ext_vector_type(8))) short short8;
typedef __attribute__((ext_vector_type(4))) float f32x4;

#define MF(a, b, c) __builtin_amdgcn_mfma_f32_16x16x32_bf16(a, b, c, 0, 0, 0)

__device__ __forceinline__ short bf16rne(float f) {
  union { float f; unsigned u; } v; v.f = f;
  unsigned r = v.u + 0x7FFFu + ((v.u >> 16) & 1u);
  return (short)(r >> 16);
}

__device__ __forceinline__ short bf16c(float f) {
  __hip_bfloat16 h = __float2bfloat16(f);
  return *reinterpret_cast<short*>(&h);
}

__device__ __forceinline__ float fast_gelu(float x) {
  float x2 = x * x;
  float z = 0.7978845608028654f * x * (1.f + 0.044715f * x2);
  float e = __expf(2.f * z);  // tanh(z) = 1 - 2/(e^{2z}+1)
  float t = 1.f - 2.f * __builtin_amdgcn_rcpf(e + 1.f);
  return 0.5f * x * (1.f + t);
}

// ---- packing for difficulty/slot_mask (fragment-array layout) ----
__global__ void pack_weight(const float* __restrict__ W, short* __restrict__ P,
                            int K, int N) {
  int id = blockIdx.x * 256 + threadIdx.x;
  int KC = K >> 5, T = N >> 4;
  if (id >= T * KC * 64) return;
  int l = id & 63, kc = (id >> 6) % KC, t = id / (64 * KC);
  int g = l >> 4, n = l & 15;
  short8 o;
#pragma unroll
  for (int jj = 0; jj < 8; jj++) {
    int k = 32 * kc + 4 * g + (jj & 3) + 16 * (jj >> 2);
    o[jj] = bf16rne(W[(size_t)k * N + 16 * t + n]);
  }
  *(short8*)(P + (size_t)id * 8) = o;
}

// ---- pack reasoning weights, consumption order v2 (Wo interleaved/head) ----
__global__ void pack_stream(const float* __restrict__ Wq, const float* __restrict__ Wk,
                            const float* __restrict__ Wv, const float* __restrict__ Wo,
                            const float* __restrict__ Wf1, const float* __restrict__ Wf2,
                            short* __restrict__ S) {
  int id = blockIdx.x * 256 + threadIdx.x;
  int f = id >> 6, lane = id & 63;
  if (f >= 1536) return;
  const float* W; int ldN, t, kc;
  if (f < 512) {
    int head = f >> 7, rem = f & 127;
    if (rem < 96) {
      int mat = rem / 32, r2 = rem % 32;
      t = 4 * head + (r2 >> 3);
      kc = r2 & 7; ldN = 256;
      W = (mat == 0) ? Wq : (mat == 1) ? Wk : Wv;
    } else {
      int r2 = rem - 96;             // 0..31
      int ch = r2 >> 4, floc = r2 & 15;
      t = ch * 8 + (floc >> 1);
      kc = 2 * head + (floc & 1);
      ldN = 256; W = Wo;
    }
  } else {
    int gg = f - 512, hc = gg / 32, r2 = gg % 32;
    if (r2 < 16) { W = Wf1; ldN = 1024; t = 2 * hc + (r2 >> 3); kc = r2 & 7; }
    else         { W = Wf2; ldN = 256;  t = r2 - 16;            kc = hc;    }
  }
  int g = lane >> 4, n = lane & 15;
  short8 o;
#pragma unroll
  for (int jj = 0; jj < 8; jj++) {
    int k = 32 * kc + 4 * g + (jj & 3) + 16 * (jj >> 2);
    o[jj] = bf16rne(W[(size_t)k * ldN + 16 * t + n]);
  }
  *(short8*)(S + (size_t)f * 512 + lane * 8) = o;
}

__device__ __forceinline__ short8 ldfrag(const short* __restrict__ P, int t, int kc,
                                         int KC, int lane) {
  return *(const short8*)(P + ((size_t)((t * KC + kc) * 64 + lane) << 3));
}

__global__ void init_accum_kernel(float* accum) {
  if (threadIdx.x < 4) accum[threadIdx.x] = 0.f;
}

__global__ void sproj_kernel(const float* __restrict__ s, const float* __restrict__ Ws,
                             float* __restrict__ sproj) {
  int p = blockIdx.x, tid = threadIdx.x;
  const float* row = s + (size_t)p * 1024;
  float sum = 0.f;
#pragma unroll
  for (int k0 = 0; k0 < 1024; k0 += 256) sum += row[k0 + tid] * Ws[k0 + tid];
#pragma unroll
  for (int m = 1; m < 64; m <<= 1) sum += __shfl_xor(sum, m, 64);
  __shared__ float red[4];
  if ((tid & 63) == 0) red[tid >> 6] = sum;
  __syncthreads();
  if (tid == 0) sproj[p] = red[0] + red[1] + red[2] + red[3];
}

__global__ void difficulty_mfma(const float* __restrict__ s, const short* __restrict__ PWd1,
                                const float* __restrict__ bd1, const float* __restrict__ Wd2,
                                const float* __restrict__ bd2, float* __restrict__ probsv,
                                float* __restrict__ accum) {
  int tid = threadIdx.x;
  int wave = tid >> 6, lane = tid & 63, n = lane & 15, g = lane >> 4;
  int p0 = (blockIdx.x * 4 + wave) * 16;
  const float* sg = s + (size_t)(p0 + n) * 1024;
  f32x4 ha[8];
  const f32x4 Z = {0.f, 0.f, 0.f, 0.f};
#pragma unroll
  for (int t = 0; t < 8; t++) ha[t] = Z;
  for (int kc = 0; kc < 32; kc++) {
    f32x4 x0 = *(const f32x4*)(sg + 32 * kc + 4 * g);
    f32x4 x1 = *(const f32x4*)(sg + 32 * kc + 16 + 4 * g);
    short8 sb;
#pragma unroll
    for (int c = 0; c < 4; c++) { sb[c] = bf16c(x0[c]); sb[c + 4] = bf16c(x1[c]); }
#pragma unroll
    for (int t = 0; t < 8; t++) ha[t] = MF(ldfrag(PWd1, t, kc, 32, lane), sb, ha[t]);
  }
  float v0 = 0.f, v1 = 0.f, v2 = 0.f;
#pragma unroll
  for (int t = 0; t < 8; t++)
#pragma unroll
    for (int c = 0; c < 4; c++) {
      int hid = 16 * t + 4 * g + c;
      float u = fmaxf(ha[t][c] + bd1[hid], 0.f);
      v0 += u * Wd2[hid * 3 + 0];
      v1 += u * Wd2[hid * 3 + 1];
      v2 += u * Wd2[hid * 3 + 2];
    }
  v0 += __shfl_xor(v0, 16, 64); v0 += __shfl_xor(v0, 32, 64);
  v1 += __shfl_xor(v1, 16, 64); v1 += __shfl_xor(v1, 32, 64);
  v2 += __shfl_xor(v2, 16, 64); v2 += __shfl_xor(v2, 32, 64);
  if (g == 0) {
    float l0 = v0 + bd2[0], l1 = v1 + bd2[1], l2 = v2 + bd2[2];
    float mx = fmaxf(l0, fmaxf(l1, l2));
    float e0 = __expf(l0 - mx), e1 = __expf(l1 - mx), e2 = __expf(l2 - mx);
    float inv = 1.f / (e0 + e1 + e2);
    float p0v = e0 * inv, p1v = e1 * inv, p2v = e2 * inv;
    int p = p0 + n;
    probsv[p * 3 + 0] = p0v; probsv[p * 3 + 1] = p1v; probsv[p * 3 + 2] = p2v;
    atomicAdd(accum + 0, p0v);
    atomicAdd(accum + 1, p1v);
    atomicAdd(accum + 2, p2v);
    atomicAdd(accum + 3, p0v * 1.f + p1v * 2.f + p2v * 4.f);
  }
}

__global__ void slot_mask_mfma(const float* __restrict__ r, const short* __restrict__ PWa1,
                               const float* __restrict__ ba1, const float* __restrict__ Wa2,
                               const float* __restrict__ ba2, const float* __restrict__ sproj,
                               float* __restrict__ mask) {
  int tid = threadIdx.x;
  int wave = tid >> 6, lane = tid & 63, n = lane & 15, g = lane >> 4;
  int p = blockIdx.x * 4 + wave;
  const float* rsg = r + (size_t)p * 4096 + n * 256;
  short8 rb[8];
#pragma unroll
  for (int kc = 0; kc < 8; kc++) {
    f32x4 x0 = *(const f32x4*)(rsg + 32 * kc + 4 * g);
    f32x4 x1 = *(const f32x4*)(rsg + 32 * kc + 16 + 4 * g);
    short8 o;
#pragma unroll
    for (int c = 0; c < 4; c++) { o[c] = bf16c(x0[c]); o[c + 4] = bf16c(x1[c]); }
    rb[kc] = o;
  }
  f32x4 ha[8];
  const f32x4 Z = {0.f, 0.f, 0.f, 0.f};
#pragma unroll
  for (int t = 0; t < 8; t++) ha[t] = Z;
#pragma unroll
  for (int kc = 0; kc < 8; kc++)
#pragma unroll
    for (int t = 0; t < 8; t++) ha[t] = MF(ldfrag(PWa1, t, kc, 8, lane), rb[kc], ha[t]);
  float v = 0.f;
#pragma unroll
  for (int t = 0; t < 8; t++)
#pragma unroll
    for (int c = 0; c < 4; c++) {
      int hid = 16 * t + 4 * g + c;
      v += fmaxf(ha[t][c] + ba1[hid], 0.f) * Wa2[hid];
    }
  v += __shfl_xor(v, 16, 64);
  v += __shfl_xor(v, 32, 64);
  if (g == 0) mask[p * 16 + n] = 1.f / (1.f + __expf(-(v + ba2[0] + sproj[p])));
}

// ================= fused 4-step reasoning kernel, 2 pos/wave =================
struct BufPair { const short* B0; const short* B1; };

__global__ __launch_bounds__(256, 2) void reason_all(
    const float* __restrict__ r_src, const float* __restrict__ maskg,
    const float* __restrict__ probsv, float* __restrict__ outp,
    const short* __restrict__ Wstream,
    const float* __restrict__ ln1s, const float* __restrict__ ln1b,
    const float* __restrict__ ln2s, const float* __restrict__ ln2b,
    const float* __restrict__ bf1g, const float* __restrict__ bf2g) {
  __shared__ __align__(16) short Wbuf[4 * 8192];  // 4 x 16KB ring = 64KB
  __shared__ __align__(16) float P_ln1s[256], P_ln1b[256], P_ln2s[256], P_ln2b[256];
  __shared__ __align__(16) float P_bf1[1024], P_bf2[256];
  const int tid = threadIdx.x;
  P_ln1s[tid] = ln1s[tid]; P_ln1b[tid] = ln1b[tid];
  P_ln2s[tid] = ln2s[tid]; P_ln2b[tid] = ln2b[tid];
  P_bf2[tid] = bf2g[tid];
  for (int i = tid; i < 1024; i += 256) P_bf1[i] = bf1g[i];
  __syncthreads();

  const int wave = tid >> 6, lane = tid & 63;
  const int n = lane & 15, g = lane >> 4;
  const int pA = blockIdx.x * 8 + wave * 2, pB = pA + 1;
  const size_t baseA = (size_t)pA * 4096, baseB = (size_t)pB * 4096;
  const f32x4 Z = {0.f, 0.f, 0.f, 0.f};

  auto stage_issue = [&](int c) {
    const short* gs = Wstream + (size_t)(c % 96) * 8192 + wave * 2048 + lane * 8;
    short* ld = (short*)Wbuf + (c & 3) * 8192 + wave * 2048;  // wave-uniform dest
#pragma unroll
    for (int i = 0; i < 4; ++i)
      __builtin_amdgcn_global_load_lds(
          (const __attribute__((address_space(1))) void*)(gs + i * 512),
          (__attribute__((address_space(3))) void*)(ld + i * 512), 16, 0, 0);
  };
  stage_issue(0); stage_issue(1);

  // ---- r for both positions -> regs ----
  f32x4 rA0[8], rA1[8], rB0[8], rB1[8];
  {
    const float* ra = r_src + baseA + n * 256;
    const float* rb = r_src + baseB + n * 256;
#pragma unroll
    for (int kc = 0; kc < 8; kc++) {
      rA0[kc] = *(const f32x4*)(ra + 32 * kc + 4 * g);
      rA1[kc] = *(const f32x4*)(ra + 32 * kc + 16 + 4 * g);
      rB0[kc] = *(const f32x4*)(rb + 32 * kc + 4 * g);
      rB1[kc] = *(const f32x4*)(rb + 32 * kc + 16 + 4 * g);
    }
  }
  const float maskA = maskg[pA * 16 + n];
  const float maskB = maskg[pB * 16 + n];

  // paired-chunk boundary: consume chunks (2s, 2s+1); stage (2s+2, 2s+3)
  int sctr = 0;
  auto boundary2 = [&]() -> BufPair {
    int c = 2 * (sctr++);
    asm volatile("s_waitcnt vmcnt(0) lgkmcnt(0)\ns_barrier" ::: "memory");
    __builtin_amdgcn_sched_barrier(0);
    if (c + 2 < NCHUNK) stage_issue(c + 2);
    if (c + 3 < NCHUNK) stage_issue(c + 3);
    BufPair bp;
    bp.B0 = &Wbuf[(c & 3) * 8192];
    bp.B1 = &Wbuf[((c + 1) & 3) * 8192];
    return bp;
  };
#define FRAG(Bp, i) (*(const short8*)((Bp) + (i) * 512 + lane * 8))

  short8 hA[8], hB[8];
  auto do_ln = [&](const f32x4* r0, const f32x4* r1, const float* sc,
                   const float* bi, short8* h) {
    float sum = 0.f, sq = 0.f;
#pragma unroll
    for (int kc = 0; kc < 8; kc++)
#pragma unroll
      for (int c = 0; c < 4; c++) {
        sum += r0[kc][c] + r1[kc][c];
        sq += r0[kc][c] * r0[kc][c] + r1[kc][c] * r1[kc][c];
      }
    sum += __shfl_xor(sum, 16, 64); sq += __shfl_xor(sq, 16, 64);
    sum += __shfl_xor(sum, 32, 64); sq += __shfl_xor(sq, 32, 64);
    float mu = sum * (1.f / 256.f);
    float inv = rsqrtf(sq * (1.f / 256.f) - mu * mu + 1e-5f);
#pragma unroll
    for (int kc = 0; kc < 8; kc++) {
      f32x4 s0 = *(const f32x4*)&sc[32 * kc + 4 * g];
      f32x4 b0 = *(const f32x4*)&bi[32 * kc + 4 * g];
      f32x4 s1 = *(const f32x4*)&sc[32 * kc + 16 + 4 * g];
      f32x4 b1 = *(const f32x4*)&bi[32 * kc + 16 + 4 * g];
      short8 hh;
#pragma unroll
      for (int c = 0; c < 4; c++) {
        hh[c]     = bf16c((r0[kc][c] - mu) * inv * s0[c] + b0[c]);
        hh[c + 4] = bf16c((r1[kc][c] - mu) * inv * s1[c] + b1[c]);
      }
      h[kc] = hh;
    }
  };

#pragma unroll 1
  for (int sidx = 0; sidx < 4; ++sidx) {
    // ================= attention (Wo folded per head) =================
    do_ln(rA0, rA1, P_ln1s, P_ln1b, hA);
    do_ln(rB0, rB1, P_ln1s, P_ln1b, hB);

#pragma unroll 1
    for (int hh = 0; hh < 4; ++hh) {
      short8 qbA[2], qbB[2], kbA[2], kbB[2];
      // ---- Q (one paired boundary: tp0 from B0, tp1 from B1) ----
      {
        BufPair P = boundary2();
        const short* Bq[2] = {P.B0, P.B1};
#pragma unroll
        for (int tp = 0; tp < 2; ++tp) {
          const short* Bp = Bq[tp];
          f32x4 a0A = Z, a1A = Z, a0B = Z, a1B = Z;
#pragma unroll
          for (int kc = 0; kc < 8; kc++) {
            short8 fr = FRAG(Bp, kc);
            a0A = MF(fr, hA[kc], a0A); a0B = MF(fr, hB[kc], a0B);
          }
#pragma unroll
          for (int kc = 0; kc < 8; kc++) {
            short8 fr = FRAG(Bp, 8 + kc);
            a1A = MF(fr, hA[kc], a1A); a1B = MF(fr, hB[kc], a1B);
          }
          short8 xA, xB;
#pragma unroll
          for (int jj = 0; jj < 8; jj++) {
            xA[jj] = bf16c(jj < 4 ? a0A[jj & 3] : a1A[jj & 3]);
            xB[jj] = bf16c(jj < 4 ? a0B[jj & 3] : a1B[jj & 3]);
          }
          qbA[tp] = xA; qbB[tp] = xB;
        }
      }
      // ---- K ----
      {
        BufPair P = boundary2();
        const short* Bq[2] = {P.B0, P.B1};
#pragma unroll
        for (int tp = 0; tp < 2; ++tp) {
          const short* Bp = Bq[tp];
          f32x4 a0A = Z, a1A = Z, a0B = Z, a1B = Z;
#pragma unroll
          for (int kc = 0; kc < 8; kc++) {
            short8 fr = FRAG(Bp, kc);
            a0A = MF(fr, hA[kc], a0A); a0B = MF(fr, hB[kc], a0B);
          }
#pragma unroll
          for (int kc = 0; kc < 8; kc++) {
            short8 fr = FRAG(Bp, 8 + kc);
            a1A = MF(fr, hA[kc], a1A); a1B = MF(fr, hB[kc], a1B);
          }
          short8 xA, xB;
#pragma unroll
          for (int jj = 0; jj < 8; jj++) {
            xA[jj] = bf16c(jj < 4 ? a0A[jj & 3] : a1A[jj & 3]);
            xB[jj] = bf16c(jj < 4 ? a0B[jj & 3] : a1B[jj & 3]);
          }
          kbA[tp] = xA; kbB[tp] = xB;
        }
      }
      // ---- scores + softmax per pos ----
      short8 pbA, pbB;
      {
        f32x4 sc1 = Z;
        sc1 = MF(kbA[0], qbA[0], sc1);
        sc1 = MF(kbA[1], qbA[1], sc1);
#pragma unroll
        for (int c = 0; c < 4; c++) sc1[c] *= 0.125f;
        float mx = fmaxf(fmaxf(sc1[0], sc1[1]), fmaxf(sc1[2], sc1[3]));
        mx = fmaxf(mx, __shfl_xor(mx, 16, 64));
        mx = fmaxf(mx, __shfl_xor(mx, 32, 64));
        float e0 = __expf(sc1[0] - mx), e1 = __expf(sc1[1] - mx);
        float e2 = __expf(sc1[2] - mx), e3 = __expf(sc1[3] - mx);
        float sm = e0 + e1 + e2 + e3;
        sm += __shfl_xor(sm, 16, 64);
        sm += __shfl_xor(sm, 32, 64);
        float isv = __builtin_amdgcn_rcpf(sm);
        pbA[0] = bf16c(e0 * isv); pbA[1] = bf16c(e1 * isv);
        pbA[2] = bf16c(e2 * isv); pbA[3] = bf16c(e3 * isv);
        pbA[4] = 0; pbA[5] = 0; pbA[6] = 0; pbA[7] = 0;
      }
      {
        f32x4 sc1 = Z;
        sc1 = MF(kbB[0], qbB[0], sc1);
        sc1 = MF(kbB[1], qbB[1], sc1);
#pragma unroll
        for (int c = 0; c < 4; c++) sc1[c] *= 0.125f;
        float mx = fmaxf(fmaxf(sc1[0], sc1[1]), fmaxf(sc1[2], sc1[3]));
        mx = fmaxf(mx, __shfl_xor(mx, 16, 64));
        mx = fmaxf(mx, __shfl_xor(mx, 32, 64));
        float e0 = __expf(sc1[0] - mx), e1 = __expf(sc1[1] - mx);
        float e2 = __expf(sc1[2] - mx), e3 = __expf(sc1[3] - mx);
        float sm = e0 + e1 + e2 + e3;
        sm += __shfl_xor(sm, 16, 64);
        sm += __shfl_xor(sm, 32, 64);
        float isv = __builtin_amdgcn_rcpf(sm);
        pbB[0] = bf16c(e0 * isv); pbB[1] = bf16c(e1 * isv);
        pbB[2] = bf16c(e2 * isv); pbB[3] = bf16c(e3 * isv);
        pbB[4] = 0; pbB[5] = 0; pbB[6] = 0; pbB[7] = 0;
      }
      // ---- V + PV -> o-slices (mask folded), one paired boundary ----
      short8 osA[2], osB[2];
      {
        BufPair P = boundary2();
        const short* Bq[2] = {P.B0, P.B1};
#pragma unroll
        for (int tp = 0; tp < 2; ++tp) {
          const short* Bp = Bq[tp];
          f32x4 v0A = Z, v1A = Z, v0B = Z, v1B = Z;
#pragma unroll
          for (int kc = 0; kc < 8; kc++) {
            short8 fr = FRAG(Bp, kc);
            v0A = MF(hA[kc], fr, v0A); v0B = MF(hB[kc], fr, v0B);
          }
#pragma unroll
          for (int kc = 0; kc < 8; kc++) {
            short8 fr = FRAG(Bp, 8 + kc);
            v1A = MF(hA[kc], fr, v1A); v1B = MF(hB[kc], fr, v1B);
          }
          short8 vb0A, vb1A, vb0B, vb1B;
#pragma unroll
          for (int c = 0; c < 4; c++) {
            vb0A[c] = bf16c(v0A[c]); vb1A[c] = bf16c(v1A[c]);
            vb0B[c] = bf16c(v0B[c]); vb1B[c] = bf16c(v1B[c]);
            vb0A[c + 4] = 0; vb1A[c + 4] = 0; vb0B[c + 4] = 0; vb1B[c + 4] = 0;
          }
          f32x4 oh0A = MF(vb0A, pbA, Z), oh1A = MF(vb1A, pbA, Z);
          f32x4 oh0B = MF(vb0B, pbB, Z), oh1B = MF(vb1B, pbB, Z);
          short8 yA, yB;
#pragma unroll
          for (int jj = 0; jj < 8; jj++) {
            yA[jj] = bf16c(maskA * (jj < 4 ? oh0A[jj & 3] : oh1A[jj & 3]));
            yB[jj] = bf16c(maskB * (jj < 4 ? oh0B[jj & 3] : oh1B[jj & 3]));
          }
          osA[tp] = yA; osB[tp] = yB;
        }
      }
      // ---- Wo fold: r += os @ Wo[head rows], one paired boundary ----
      {
        BufPair P = boundary2();
        const short* Bq[2] = {P.B0, P.B1};
#pragma unroll
        for (int ch = 0; ch < 2; ++ch) {
          const short* Bp = Bq[ch];
#pragma unroll
          for (int tloc = 0; tloc < 8; ++tloc) {
            short8 f0 = FRAG(Bp, 2 * tloc), f1 = FRAG(Bp, 2 * tloc + 1);
            int kk = ch * 4 + (tloc >> 1);
            if ((tloc & 1) == 0) {
              rA0[kk] = MF(f0, osA[0], rA0[kk]); rA0[kk] = MF(f1, osA[1], rA0[kk]);
              rB0[kk] = MF(f0, osB[0], rB0[kk]); rB0[kk] = MF(f1, osB[1], rB0[kk]);
            } else {
              rA1[kk] = MF(f0, osA[0], rA1[kk]); rA1[kk] = MF(f1, osA[1], rA1[kk]);
              rB1[kk] = MF(f0, osB[0], rB1[kk]); rB1[kk] = MF(f1, osB[1], rB1[kk]);
            }
          }
        }
      }
    }

    // ================= FFN =================
    do_ln(rA0, rA1, P_ln2s, P_ln2b, hA);
    do_ln(rB0, rB1, P_ln2s, P_ln2b, hB);
#pragma unroll 1
    for (int hc = 0; hc < 32; hc++) {
      // one paired boundary: Wf1 from B0, Wf2 from B1 (gelu overlaps B1 reads)
      BufPair P = boundary2();
      f32x4 t0A = Z, t1A = Z, t0B = Z, t1B = Z;
      {
        const short* Bp = P.B0;
#pragma unroll
        for (int kc = 0; kc < 8; kc++) {
          short8 fr = FRAG(Bp, kc);
          t0A = MF(fr, hA[kc], t0A); t0B = MF(fr, hB[kc], t0B);
        }
#pragma unroll
        for (int kc = 0; kc < 8; kc++) {
          short8 fr = FRAG(Bp, 8 + kc);
          t1A = MF(fr, hA[kc], t1A); t1B = MF(fr, hB[kc], t1B);
        }
      }
      f32x4 u0 = *(const f32x4*)&P_bf1[32 * hc + 4 * g];
      f32x4 u1 = *(const f32x4*)&P_bf1[32 * hc + 16 + 4 * g];
      short8 hbbA, hbbB;
#pragma unroll
      for (int c = 0; c < 4; c++) {
        hbbA[c]     = bf16c(maskA * fast_gelu(t0A[c] + u0[c]));
        hbbA[c + 4] = bf16c(maskA * fast_gelu(t1A[c] + u1[c]));
        hbbB[c]     = bf16c(maskB * fast_gelu(t0B[c] + u0[c]));
        hbbB[c + 4] = bf16c(maskB * fast_gelu(t1B[c] + u1[c]));
      }
      {
        const short* Bp = P.B1;
#pragma unroll
        for (int tt = 0; tt < 8; tt++) {
          short8 f0 = FRAG(Bp, 2 * tt), f1 = FRAG(Bp, 2 * tt + 1);
          rA0[tt] = MF(f0, hbbA, rA0[tt]); rB0[tt] = MF(f0, hbbB, rB0[tt]);
          rA1[tt] = MF(f1, hbbA, rA1[tt]); rB1[tt] = MF(f1, hbbB, rB1[tt]);
        }
      }
    }
    // ---- FFN bias residual ----
#pragma unroll
    for (int kc = 0; kc < 8; kc++) {
      f32x4 b0 = *(const f32x4*)&P_bf2[32 * kc + 4 * g];
      f32x4 b1 = *(const f32x4*)&P_bf2[32 * kc + 16 + 4 * g];
#pragma unroll
      for (int c = 0; c < 4; c++) {
        rA0[kc][c] += maskA * b0[c]; rA1[kc][c] += maskA * b1[c];
        rB0[kc][c] += maskB * b0[c]; rB1[kc][c] += maskB * b1[c];
      }
    }

    // ---- candidate combine ----
    if (sidx == 0) {
      float wa = probsv[pA * 3 + 0], wb = probsv[pB * 3 + 0];
      float* oa = outp + baseA + n * 256;
      float* ob2 = outp + baseB + n * 256;
#pragma unroll
      for (int kc = 0; kc < 8; kc++) {
        f32x4 xa0, xa1, xb0, xb1;
#pragma unroll
        for (int c = 0; c < 4; c++) {
          xa0[c] = wa * rA0[kc][c]; xa1[c] = wa * rA1[kc][c];
          xb0[c] = wb * rB0[kc][c]; xb1[c] = wb * rB1[kc][c];
        }
        *(f32x4*)(oa + 32 * kc + 4 * g) = xa0;
        *(f32x4*)(oa + 32 * kc + 16 + 4 * g) = xa1;
        *(f32x4*)(ob2 + 32 * kc + 4 * g) = xb0;
        *(f32x4*)(ob2 + 32 * kc + 16 + 4 * g) = xb1;
      }
    } else if (sidx == 1 || sidx == 3) {
      int ci = (sidx == 1) ? 1 : 2;
      float wa = probsv[pA * 3 + ci], wb = probsv[pB * 3 + ci];
      float* oa = outp + baseA + n * 256;
      float* ob2 = outp + baseB + n * 256;
#pragma unroll
      for (int kc = 0; kc < 8; kc++) {
        f32x4 xa0 = *(f32x4*)(oa + 32 * kc + 4 * g);
        f32x4 xa1 = *(f32x4*)(oa + 32 * kc + 16 + 4 * g);
        f32x4 xb0 = *(f32x4*)(ob2 + 32 * kc + 4 * g);
        f32x4 xb1 = *(f32x4*)(ob2 + 32 * kc + 16 + 4 * g);
#pragma unroll
        for (int c = 0; c < 4; c++) {
          xa0[c] += wa * rA0[kc][c]; xa1[c] += wa * rA1[kc][c];
          xb0[c] += wb * rB0[kc][c]; xb1[c] += wb * rB1[kc][c];
        }
        *(f32x4*)(oa + 32 * kc + 4 * g) = xa0;
        *(f32x4*)(oa + 32 * kc + 16 + 4 * g) = xa1;
        *(f32x4*)(ob2 + 32 * kc + 4 * g) = xb0;
        *(f32x4*)(ob2 + 32 * kc + 16 + 4 * g) = xb1;
      }
    }
  }
}

__global__ void finalize_kernel(const float* __restrict__ accum, float* __restrict__ dst) {
  const float inv = 1.f / 4096.f;
  float m0 = accum[0] * inv, m1 = accum[1] * inv, m2 = accum[2] * inv;
  const float u = 1.f / 3.f;
  float d0 = m0 - u, d1 = m1 - u, d2 = m2 - u;
  dst[0] = (d0 * d0 + d1 * d1 + d2 * d2) * (1.f / 3.f);
  dst[1] = accum[3] * inv;
}

extern "C" void kernel_launch(void* const* d_in, const int* in_sizes, int n_in,
                              void* d_out, int out_size, void* d_ws, size_t ws_size,
                              hipStream_t stream) {
  const float* s    = (const float*)d_in[0];
  const float* r    = (const float*)d_in[1];
  const float* Wd1  = (const float*)d_in[2];
  const float* bd1  = (const float*)d_in[3];
  const float* Wd2  = (const float*)d_in[4];
  const float* bd2  = (const float*)d_in[5];
  const float* Wa1  = (const float*)d_in[6];
  const float* ba1  = (const float*)d_in[7];
  const float* Wa2  = (const float*)d_in[8];
  const float* ba2  = (const float*)d_in[9];
  const float* Wsp  = (const float*)d_in[10];
  const float* ln1s = (const float*)d_in[11];
  const float* ln1b = (const float*)d_in[12];
  const float* Wq   = (const float*)d_in[13];
  const float* Wk   = (const float*)d_in[14];
  const float* Wv   = (const float*)d_in[15];
  const float* Wo   = (const float*)d_in[16];
  const float* ln2s = (const float*)d_in[17];
  const float* ln2b = (const float*)d_in[18];
  const float* Wf1  = (const float*)d_in[19];
  const float* bf1  = (const float*)d_in[20];
  const float* Wf2  = (const float*)d_in[21];
  const float* bf2  = (const float*)d_in[22];

  float* out = (float*)d_out;
  float* wsf = (float*)d_ws;
  float* mask   = wsf;
  float* sproj  = wsf + 65536;
  float* probsv = wsf + 65536 + 4096;
  float* accum  = wsf + 65536 + 4096 + 12288;
  short* pk     = (short*)(wsf + 131072);
  short* Wstream = pk;             // 786432 shorts (1536 x 1KB frags)
  short* PWa1    = pk + 786432;    // 32768
  short* PWd1    = pk + 819200;    // 131072

  pack_stream<<<384, 256, 0, stream>>>(Wq, Wk, Wv, Wo, Wf1, Wf2, Wstream);
  pack_weight<<<16, 256, 0, stream>>>(Wa1, PWa1, 256, 128);
  pack_weight<<<64, 256, 0, stream>>>(Wd1, PWd1, 1024, 128);

  init_accum_kernel<<<1, 64, 0, stream>>>(accum);
  sproj_kernel<<<NPOS, 256, 0, stream>>>(s, Wsp, sproj);
  difficulty_mfma<<<64, 256, 0, stream>>>(s, PWd1, bd1, Wd2, bd2, probsv, accum);
  slot_mask_mfma<<<NPOS / 4, 256, 0, stream>>>(r, PWa1, ba1, Wa2, ba2, sproj, mask);

  reason_all<<<NPOS / 8, 256, 0, stream>>>(r, mask, probsv, out, Wstream,
                                           ln1s, ln1b, ln2s, ln2b, bf1, bf2);

  finalize_kernel<<<1, 1, 0, stream>>>(accum, out + R_ELEMS);
}

// Round 13
// 586.508 us; speedup vs baseline: 3.1958x; 1.1152x over previous
//
#include <hip/hip_runtime.h>
#include <hip/hip_bf16.h>
#include <math.h>

// ============================================================================
// AuroraBlock round 13: EXACT round-8 champion restoration (576us reason_all).
//   - 2 pos/wave, paired 16KB chunks, ring-4 LDS (64KB), vmcnt(0)+s_barrier
//     per paired boundary, Wo folded per head, r f32 in regs across 4 steps,
//     s_setprio(1) around MFMA clusters (r12 proved removal costs ~9%).
//   - Falsified variants: finer phases (r7 +4%), barrier-free private staging
//     (r9 +24%), cross-block stagger (r10 null), L2->VGPR no-LDS (r11 +180%),
//     no-setprio (r12 +9%).
// ws (floats): [0..65535] mask | [65536..69631] sproj | [69632..81919] probs
//   [81920..81923] accum | shorts at float offset 131072:
//   Wstream(786432) PWa1(32768) PWd1(131072)
// d_out: [0..16777215] r_out, [16777216] routing_loss, [16777217] mean_k
// ============================================================================

#define NPOS 4096
#define R_ELEMS 16777216ull
#define NCHUNK 384  // 16KB chunks total (96/step * 4 steps)

typedef __attribute__((ext_vector_type(8))) short short8;
typedef __attribute__((ext_vector_type(4))) float f32x4;

#define MF(a, b, c) __builtin_amdgcn_mfma_f32_16x16x32_bf16(a, b, c, 0, 0, 0)

__device__ __forceinline__ short bf16rne(float f) {
  union { float f; unsigned u; } v; v.f = f;
  unsigned r = v.u + 0x7FFFu + ((v.u >> 16) & 1u);
  return (short)(r >> 16);
}

__device__ __forceinline__ short bf16c(float f) {
  __hip_bfloat16 h = __float2bfloat16(f);
  return *reinterpret_cast<short*>(&h);
}

__device__ __forceinline__ float fast_gelu(float x) {
  float x2 = x * x;
  float z = 0.7978845608028654f * x * (1.f + 0.044715f * x2);
  float e = __expf(2.f * z);  // tanh(z) = 1 - 2/(e^{2z}+1)
  float t = 1.f - 2.f * __builtin_amdgcn_rcpf(e + 1.f);
  return 0.5f * x * (1.f + t);
}

// ---- packing for difficulty/slot_mask (fragment-array layout) ----
__global__ void pack_weight(const float* __restrict__ W, short* __restrict__ P,
                            int K, int N) {
  int id = blockIdx.x * 256 + threadIdx.x;
  int KC = K >> 5, T = N >> 4;
  if (id >= T * KC * 64) return;
  int l = id & 63, kc = (id >> 6) % KC, t = id / (64 * KC);
  int g = l >> 4, n = l & 15;
  short8 o;
#pragma unroll
  for (int jj = 0; jj < 8; jj++) {
    int k = 32 * kc + 4 * g + (jj & 3) + 16 * (jj >> 2);
    o[jj] = bf16rne(W[(size_t)k * N + 16 * t + n]);
  }
  *(short8*)(P + (size_t)id * 8) = o;
}

// ---- pack reasoning weights, consumption order v2 (Wo interleaved/head) ----
// 1536 frags: [head 0..3]: q(32: tp*16+tt*8+kc), k(32), v(32),
//                          Wo-rows (32: ch*16 + tloc*2 + kcl; t=ch*8+tloc,
//                          kc=2*head+kcl)   = 128/head
//             FFN: per hc(32): Wf1 (16: tt*8+kc, t=2hc+tt), Wf2 (16: t, kc=hc)
__global__ void pack_stream(const float* __restrict__ Wq, const float* __restrict__ Wk,
                            const float* __restrict__ Wv, const float* __restrict__ Wo,
                            const float* __restrict__ Wf1, const float* __restrict__ Wf2,
                            short* __restrict__ S) {
  int id = blockIdx.x * 256 + threadIdx.x;
  int f = id >> 6, lane = id & 63;
  if (f >= 1536) return;
  const float* W; int ldN, t, kc;
  if (f < 512) {
    int head = f >> 7, rem = f & 127;
    if (rem < 96) {
      int mat = rem / 32, r2 = rem % 32;
      t = 4 * head + (r2 >> 3);
      kc = r2 & 7; ldN = 256;
      W = (mat == 0) ? Wq : (mat == 1) ? Wk : Wv;
    } else {
      int r2 = rem - 96;             // 0..31
      int ch = r2 >> 4, floc = r2 & 15;
      t = ch * 8 + (floc >> 1);
      kc = 2 * head + (floc & 1);
      ldN = 256; W = Wo;
    }
  } else {
    int gg = f - 512, hc = gg / 32, r2 = gg % 32;
    if (r2 < 16) { W = Wf1; ldN = 1024; t = 2 * hc + (r2 >> 3); kc = r2 & 7; }
    else         { W = Wf2; ldN = 256;  t = r2 - 16;            kc = hc;    }
  }
  int g = lane >> 4, n = lane & 15;
  short8 o;
#pragma unroll
  for (int jj = 0; jj < 8; jj++) {
    int k = 32 * kc + 4 * g + (jj & 3) + 16 * (jj >> 2);
    o[jj] = bf16rne(W[(size_t)k * ldN + 16 * t + n]);
  }
  *(short8*)(S + (size_t)f * 512 + lane * 8) = o;
}

__device__ __forceinline__ short8 ldfrag(const short* __restrict__ P, int t, int kc,
                                         int KC, int lane) {
  return *(const short8*)(P + ((size_t)((t * KC + kc) * 64 + lane) << 3));
}

__global__ void init_accum_kernel(float* accum) {
  if (threadIdx.x < 4) accum[threadIdx.x] = 0.f;
}

__global__ void sproj_kernel(const float* __restrict__ s, const float* __restrict__ Ws,
                             float* __restrict__ sproj) {
  int p = blockIdx.x, tid = threadIdx.x;
  const float* row = s + (size_t)p * 1024;
  float sum = 0.f;
#pragma unroll
  for (int k0 = 0; k0 < 1024; k0 += 256) sum += row[k0 + tid] * Ws[k0 + tid];
#pragma unroll
  for (int m = 1; m < 64; m <<= 1) sum += __shfl_xor(sum, m, 64);
  __shared__ float red[4];
  if ((tid & 63) == 0) red[tid >> 6] = sum;
  __syncthreads();
  if (tid == 0) sproj[p] = red[0] + red[1] + red[2] + red[3];
}

__global__ void difficulty_mfma(const float* __restrict__ s, const short* __restrict__ PWd1,
                                const float* __restrict__ bd1, const float* __restrict__ Wd2,
                                const float* __restrict__ bd2, float* __restrict__ probsv,
                                float* __restrict__ accum) {
  int tid = threadIdx.x;
  int wave = tid >> 6, lane = tid & 63, n = lane & 15, g = lane >> 4;
  int p0 = (blockIdx.x * 4 + wave) * 16;
  const float* sg = s + (size_t)(p0 + n) * 1024;
  f32x4 ha[8];
  const f32x4 Z = {0.f, 0.f, 0.f, 0.f};
#pragma unroll
  for (int t = 0; t < 8; t++) ha[t] = Z;
  for (int kc = 0; kc < 32; kc++) {
    f32x4 x0 = *(const f32x4*)(sg + 32 * kc + 4 * g);
    f32x4 x1 = *(const f32x4*)(sg + 32 * kc + 16 + 4 * g);
    short8 sb;
#pragma unroll
    for (int c = 0; c < 4; c++) { sb[c] = bf16c(x0[c]); sb[c + 4] = bf16c(x1[c]); }
#pragma unroll
    for (int t = 0; t < 8; t++) ha[t] = MF(ldfrag(PWd1, t, kc, 32, lane), sb, ha[t]);
  }
  float v0 = 0.f, v1 = 0.f, v2 = 0.f;
#pragma unroll
  for (int t = 0; t < 8; t++)
#pragma unroll
    for (int c = 0; c < 4; c++) {
      int hid = 16 * t + 4 * g + c;
      float u = fmaxf(ha[t][c] + bd1[hid], 0.f);
      v0 += u * Wd2[hid * 3 + 0];
      v1 += u * Wd2[hid * 3 + 1];
      v2 += u * Wd2[hid * 3 + 2];
    }
  v0 += __shfl_xor(v0, 16, 64); v0 += __shfl_xor(v0, 32, 64);
  v1 += __shfl_xor(v1, 16, 64); v1 += __shfl_xor(v1, 32, 64);
  v2 += __shfl_xor(v2, 16, 64); v2 += __shfl_xor(v2, 32, 64);
  if (g == 0) {
    float l0 = v0 + bd2[0], l1 = v1 + bd2[1], l2 = v2 + bd2[2];
    float mx = fmaxf(l0, fmaxf(l1, l2));
    float e0 = __expf(l0 - mx), e1 = __expf(l1 - mx), e2 = __expf(l2 - mx);
    float inv = 1.f / (e0 + e1 + e2);
    float p0v = e0 * inv, p1v = e1 * inv, p2v = e2 * inv;
    int p = p0 + n;
    probsv[p * 3 + 0] = p0v; probsv[p * 3 + 1] = p1v; probsv[p * 3 + 2] = p2v;
    atomicAdd(accum + 0, p0v);
    atomicAdd(accum + 1, p1v);
    atomicAdd(accum + 2, p2v);
    atomicAdd(accum + 3, p0v * 1.f + p1v * 2.f + p2v * 4.f);
  }
}

__global__ void slot_mask_mfma(const float* __restrict__ r, const short* __restrict__ PWa1,
                               const float* __restrict__ ba1, const float* __restrict__ Wa2,
                               const float* __restrict__ ba2, const float* __restrict__ sproj,
                               float* __restrict__ mask) {
  int tid = threadIdx.x;
  int wave = tid >> 6, lane = tid & 63, n = lane & 15, g = lane >> 4;
  int p = blockIdx.x * 4 + wave;
  const float* rsg = r + (size_t)p * 4096 + n * 256;
  short8 rb[8];
#pragma unroll
  for (int kc = 0; kc < 8; kc++) {
    f32x4 x0 = *(const f32x4*)(rsg + 32 * kc + 4 * g);
    f32x4 x1 = *(const f32x4*)(rsg + 32 * kc + 16 + 4 * g);
    short8 o;
#pragma unroll
    for (int c = 0; c < 4; c++) { o[c] = bf16c(x0[c]); o[c + 4] = bf16c(x1[c]); }
    rb[kc] = o;
  }
  f32x4 ha[8];
  const f32x4 Z = {0.f, 0.f, 0.f, 0.f};
#pragma unroll
  for (int t = 0; t < 8; t++) ha[t] = Z;
#pragma unroll
  for (int kc = 0; kc < 8; kc++)
#pragma unroll
    for (int t = 0; t < 8; t++) ha[t] = MF(ldfrag(PWa1, t, kc, 8, lane), rb[kc], ha[t]);
  float v = 0.f;
#pragma unroll
  for (int t = 0; t < 8; t++)
#pragma unroll
    for (int c = 0; c < 4; c++) {
      int hid = 16 * t + 4 * g + c;
      v += fmaxf(ha[t][c] + ba1[hid], 0.f) * Wa2[hid];
    }
  v += __shfl_xor(v, 16, 64);
  v += __shfl_xor(v, 32, 64);
  if (g == 0) mask[p * 16 + n] = 1.f / (1.f + __expf(-(v + ba2[0] + sproj[p])));
}

// ================= fused 4-step reasoning kernel, 2 pos/wave =================
struct BufPair { const short* B0; const short* B1; };

__global__ __launch_bounds__(256, 2) void reason_all(
    const float* __restrict__ r_src, const float* __restrict__ maskg,
    const float* __restrict__ probsv, float* __restrict__ outp,
    const short* __restrict__ Wstream,
    const float* __restrict__ ln1s, const float* __restrict__ ln1b,
    const float* __restrict__ ln2s, const float* __restrict__ ln2b,
    const float* __restrict__ bf1g, const float* __restrict__ bf2g) {
  __shared__ __align__(16) short Wbuf[4 * 8192];  // 4 x 16KB ring = 64KB
  __shared__ __align__(16) float P_ln1s[256], P_ln1b[256], P_ln2s[256], P_ln2b[256];
  __shared__ __align__(16) float P_bf1[1024], P_bf2[256];
  const int tid = threadIdx.x;
  P_ln1s[tid] = ln1s[tid]; P_ln1b[tid] = ln1b[tid];
  P_ln2s[tid] = ln2s[tid]; P_ln2b[tid] = ln2b[tid];
  P_bf2[tid] = bf2g[tid];
  for (int i = tid; i < 1024; i += 256) P_bf1[i] = bf1g[i];
  __syncthreads();

  const int wave = tid >> 6, lane = tid & 63;
  const int n = lane & 15, g = lane >> 4;
  const int pA = blockIdx.x * 8 + wave * 2, pB = pA + 1;
  const size_t baseA = (size_t)pA * 4096, baseB = (size_t)pB * 4096;
  const f32x4 Z = {0.f, 0.f, 0.f, 0.f};

  auto stage_issue = [&](int c) {
    const short* gs = Wstream + (size_t)(c % 96) * 8192 + wave * 2048 + lane * 8;
    short* ld = (short*)Wbuf + (c & 3) * 8192 + wave * 2048;  // wave-uniform dest
#pragma unroll
    for (int i = 0; i < 4; ++i)
      __builtin_amdgcn_global_load_lds(
          (const __attribute__((address_space(1))) void*)(gs + i * 512),
          (__attribute__((address_space(3))) void*)(ld + i * 512), 16, 0, 0);
  };
  stage_issue(0); stage_issue(1);

  // ---- r for both positions -> regs ----
  f32x4 rA0[8], rA1[8], rB0[8], rB1[8];
  {
    const float* ra = r_src + baseA + n * 256;
    const float* rb = r_src + baseB + n * 256;
#pragma unroll
    for (int kc = 0; kc < 8; kc++) {
      rA0[kc] = *(const f32x4*)(ra + 32 * kc + 4 * g);
      rA1[kc] = *(const f32x4*)(ra + 32 * kc + 16 + 4 * g);
      rB0[kc] = *(const f32x4*)(rb + 32 * kc + 4 * g);
      rB1[kc] = *(const f32x4*)(rb + 32 * kc + 16 + 4 * g);
    }
  }
  const float maskA = maskg[pA * 16 + n];
  const float maskB = maskg[pB * 16 + n];

  // paired-chunk boundary: consume chunks (2s, 2s+1); stage (2s+2, 2s+3)
  int sctr = 0;
  auto boundary2 = [&]() -> BufPair {
    int c = 2 * (sctr++);
    asm volatile("s_waitcnt vmcnt(0) lgkmcnt(0)\ns_barrier" ::: "memory");
    __builtin_amdgcn_sched_barrier(0);
    if (c + 2 < NCHUNK) stage_issue(c + 2);
    if (c + 3 < NCHUNK) stage_issue(c + 3);
    BufPair bp;
    bp.B0 = &Wbuf[(c & 3) * 8192];
    bp.B1 = &Wbuf[((c + 1) & 3) * 8192];
    return bp;
  };
#define FRAG(Bp, i) (*(const short8*)((Bp) + (i) * 512 + lane * 8))

  short8 hA[8], hB[8];
  auto do_ln = [&](const f32x4* r0, const f32x4* r1, const float* sc,
                   const float* bi, short8* h) {
    float sum = 0.f, sq = 0.f;
#pragma unroll
    for (int kc = 0; kc < 8; kc++)
#pragma unroll
      for (int c = 0; c < 4; c++) {
        sum += r0[kc][c] + r1[kc][c];
        sq += r0[kc][c] * r0[kc][c] + r1[kc][c] * r1[kc][c];
      }
    sum += __shfl_xor(sum, 16, 64); sq += __shfl_xor(sq, 16, 64);
    sum += __shfl_xor(sum, 32, 64); sq += __shfl_xor(sq, 32, 64);
    float mu = sum * (1.f / 256.f);
    float inv = rsqrtf(sq * (1.f / 256.f) - mu * mu + 1e-5f);
#pragma unroll
    for (int kc = 0; kc < 8; kc++) {
      f32x4 s0 = *(const f32x4*)&sc[32 * kc + 4 * g];
      f32x4 b0 = *(const f32x4*)&bi[32 * kc + 4 * g];
      f32x4 s1 = *(const f32x4*)&sc[32 * kc + 16 + 4 * g];
      f32x4 b1 = *(const f32x4*)&bi[32 * kc + 16 + 4 * g];
      short8 hh;
#pragma unroll
      for (int c = 0; c < 4; c++) {
        hh[c]     = bf16c((r0[kc][c] - mu) * inv * s0[c] + b0[c]);
        hh[c + 4] = bf16c((r1[kc][c] - mu) * inv * s1[c] + b1[c]);
      }
      h[kc] = hh;
    }
  };

#pragma unroll 1
  for (int sidx = 0; sidx < 4; ++sidx) {
    // ================= attention (Wo folded per head) =================
    do_ln(rA0, rA1, P_ln1s, P_ln1b, hA);
    do_ln(rB0, rB1, P_ln1s, P_ln1b, hB);

#pragma unroll 1
    for (int hh = 0; hh < 4; ++hh) {
      short8 qbA[2], qbB[2], kbA[2], kbB[2];
      // ---- Q (one paired boundary: tp0 from B0, tp1 from B1) ----
      {
        BufPair P = boundary2();
        const short* Bq[2] = {P.B0, P.B1};
#pragma unroll
        for (int tp = 0; tp < 2; ++tp) {
          const short* Bp = Bq[tp];
          f32x4 a0A = Z, a1A = Z, a0B = Z, a1B = Z;
          __builtin_amdgcn_s_setprio(1);
#pragma unroll
          for (int kc = 0; kc < 8; kc++) {
            short8 fr = FRAG(Bp, kc);
            a0A = MF(fr, hA[kc], a0A); a0B = MF(fr, hB[kc], a0B);
          }
#pragma unroll
          for (int kc = 0; kc < 8; kc++) {
            short8 fr = FRAG(Bp, 8 + kc);
            a1A = MF(fr, hA[kc], a1A); a1B = MF(fr, hB[kc], a1B);
          }
          __builtin_amdgcn_s_setprio(0);
          short8 xA, xB;
#pragma unroll
          for (int jj = 0; jj < 8; jj++) {
            xA[jj] = bf16c(jj < 4 ? a0A[jj & 3] : a1A[jj & 3]);
            xB[jj] = bf16c(jj < 4 ? a0B[jj & 3] : a1B[jj & 3]);
          }
          qbA[tp] = xA; qbB[tp] = xB;
        }
      }
      // ---- K ----
      {
        BufPair P = boundary2();
        const short* Bq[2] = {P.B0, P.B1};
#pragma unroll
        for (int tp = 0; tp < 2; ++tp) {
          const short* Bp = Bq[tp];
          f32x4 a0A = Z, a1A = Z, a0B = Z, a1B = Z;
          __builtin_amdgcn_s_setprio(1);
#pragma unroll
          for (int kc = 0; kc < 8; kc++) {
            short8 fr = FRAG(Bp, kc);
            a0A = MF(fr, hA[kc], a0A); a0B = MF(fr, hB[kc], a0B);
          }
#pragma unroll
          for (int kc = 0; kc < 8; kc++) {
            short8 fr = FRAG(Bp, 8 + kc);
            a1A = MF(fr, hA[kc], a1A); a1B = MF(fr, hB[kc], a1B);
          }
          __builtin_amdgcn_s_setprio(0);
          short8 xA, xB;
#pragma unroll
          for (int jj = 0; jj < 8; jj++) {
            xA[jj] = bf16c(jj < 4 ? a0A[jj & 3] : a1A[jj & 3]);
            xB[jj] = bf16c(jj < 4 ? a0B[jj & 3] : a1B[jj & 3]);
          }
          kbA[tp] = xA; kbB[tp] = xB;
        }
      }
      // ---- scores + softmax per pos ----
      short8 pbA, pbB;
      {
        f32x4 sc1 = Z;
        sc1 = MF(kbA[0], qbA[0], sc1);
        sc1 = MF(kbA[1], qbA[1], sc1);
#pragma unroll
        for (int c = 0; c < 4; c++) sc1[c] *= 0.125f;
        float mx = fmaxf(fmaxf(sc1[0], sc1[1]), fmaxf(sc1[2], sc1[3]));
        mx = fmaxf(mx, __shfl_xor(mx, 16, 64));
        mx = fmaxf(mx, __shfl_xor(mx, 32, 64));
        float e0 = __expf(sc1[0] - mx), e1 = __expf(sc1[1] - mx);
        float e2 = __expf(sc1[2] - mx), e3 = __expf(sc1[3] - mx);
        float sm = e0 + e1 + e2 + e3;
        sm += __shfl_xor(sm, 16, 64);
        sm += __shfl_xor(sm, 32, 64);
        float isv = __builtin_amdgcn_rcpf(sm);
        pbA[0] = bf16c(e0 * isv); pbA[1] = bf16c(e1 * isv);
        pbA[2] = bf16c(e2 * isv); pbA[3] = bf16c(e3 * isv);
        pbA[4] = 0; pbA[5] = 0; pbA[6] = 0; pbA[7] = 0;
      }
      {
        f32x4 sc1 = Z;
        sc1 = MF(kbB[0], qbB[0], sc1);
        sc1 = MF(kbB[1], qbB[1], sc1);
#pragma unroll
        for (int c = 0; c < 4; c++) sc1[c] *= 0.125f;
        float mx = fmaxf(fmaxf(sc1[0], sc1[1]), fmaxf(sc1[2], sc1[3]));
        mx = fmaxf(mx, __shfl_xor(mx, 16, 64));
        mx = fmaxf(mx, __shfl_xor(mx, 32, 64));
        float e0 = __expf(sc1[0] - mx), e1 = __expf(sc1[1] - mx);
        float e2 = __expf(sc1[2] - mx), e3 = __expf(sc1[3] - mx);
        float sm = e0 + e1 + e2 + e3;
        sm += __shfl_xor(sm, 16, 64);
        sm += __shfl_xor(sm, 32, 64);
        float isv = __builtin_amdgcn_rcpf(sm);
        pbB[0] = bf16c(e0 * isv); pbB[1] = bf16c(e1 * isv);
        pbB[2] = bf16c(e2 * isv); pbB[3] = bf16c(e3 * isv);
        pbB[4] = 0; pbB[5] = 0; pbB[6] = 0; pbB[7] = 0;
      }
      // ---- V + PV -> o-slices (mask folded), one paired boundary ----
      short8 osA[2], osB[2];
      {
        BufPair P = boundary2();
        const short* Bq[2] = {P.B0, P.B1};
#pragma unroll
        for (int tp = 0; tp < 2; ++tp) {
          const short* Bp = Bq[tp];
          f32x4 v0A = Z, v1A = Z, v0B = Z, v1B = Z;
          __builtin_amdgcn_s_setprio(1);
#pragma unroll
          for (int kc = 0; kc < 8; kc++) {
            short8 fr = FRAG(Bp, kc);
            v0A = MF(hA[kc], fr, v0A); v0B = MF(hB[kc], fr, v0B);
          }
#pragma unroll
          for (int kc = 0; kc < 8; kc++) {
            short8 fr = FRAG(Bp, 8 + kc);
            v1A = MF(hA[kc], fr, v1A); v1B = MF(hB[kc], fr, v1B);
          }
          __builtin_amdgcn_s_setprio(0);
          short8 vb0A, vb1A, vb0B, vb1B;
#pragma unroll
          for (int c = 0; c < 4; c++) {
            vb0A[c] = bf16c(v0A[c]); vb1A[c] = bf16c(v1A[c]);
            vb0B[c] = bf16c(v0B[c]); vb1B[c] = bf16c(v1B[c]);
            vb0A[c + 4] = 0; vb1A[c + 4] = 0; vb0B[c + 4] = 0; vb1B[c + 4] = 0;
          }
          f32x4 oh0A = MF(vb0A, pbA, Z), oh1A = MF(vb1A, pbA, Z);
          f32x4 oh0B = MF(vb0B, pbB, Z), oh1B = MF(vb1B, pbB, Z);
          short8 yA, yB;
#pragma unroll
          for (int jj = 0; jj < 8; jj++) {
            yA[jj] = bf16c(maskA * (jj < 4 ? oh0A[jj & 3] : oh1A[jj & 3]));
            yB[jj] = bf16c(maskB * (jj < 4 ? oh0B[jj & 3] : oh1B[jj & 3]));
          }
          osA[tp] = yA; osB[tp] = yB;
        }
      }
      // ---- Wo fold: r += os @ Wo[head rows], one paired boundary ----
      {
        BufPair P = boundary2();
        const short* Bq[2] = {P.B0, P.B1};
        __builtin_amdgcn_s_setprio(1);
#pragma unroll
        for (int ch = 0; ch < 2; ++ch) {
          const short* Bp = Bq[ch];
#pragma unroll
          for (int tloc = 0; tloc < 8; ++tloc) {
            short8 f0 = FRAG(Bp, 2 * tloc), f1 = FRAG(Bp, 2 * tloc + 1);
            int kk = ch * 4 + (tloc >> 1);
            if ((tloc & 1) == 0) {
              rA0[kk] = MF(f0, osA[0], rA0[kk]); rA0[kk] = MF(f1, osA[1], rA0[kk]);
              rB0[kk] = MF(f0, osB[0], rB0[kk]); rB0[kk] = MF(f1, osB[1], rB0[kk]);
            } else {
              rA1[kk] = MF(f0, osA[0], rA1[kk]); rA1[kk] = MF(f1, osA[1], rA1[kk]);
              rB1[kk] = MF(f0, osB[0], rB1[kk]); rB1[kk] = MF(f1, osB[1], rB1[kk]);
            }
          }
        }
        __builtin_amdgcn_s_setprio(0);
      }
    }

    // ================= FFN =================
    do_ln(rA0, rA1, P_ln2s, P_ln2b, hA);
    do_ln(rB0, rB1, P_ln2s, P_ln2b, hB);
#pragma unroll 1
    for (int hc = 0; hc < 32; hc++) {
      // one paired boundary: Wf1 from B0, Wf2 from B1 (gelu overlaps B1 reads)
      BufPair P = boundary2();
      f32x4 t0A = Z, t1A = Z, t0B = Z, t1B = Z;
      {
        const short* Bp = P.B0;
        __builtin_amdgcn_s_setprio(1);
#pragma unroll
        for (int kc = 0; kc < 8; kc++) {
          short8 fr = FRAG(Bp, kc);
          t0A = MF(fr, hA[kc], t0A); t0B = MF(fr, hB[kc], t0B);
        }
#pragma unroll
        for (int kc = 0; kc < 8; kc++) {
          short8 fr = FRAG(Bp, 8 + kc);
          t1A = MF(fr, hA[kc], t1A); t1B = MF(fr, hB[kc], t1B);
        }
        __builtin_amdgcn_s_setprio(0);
      }
      f32x4 u0 = *(const f32x4*)&P_bf1[32 * hc + 4 * g];
      f32x4 u1 = *(const f32x4*)&P_bf1[32 * hc + 16 + 4 * g];
      short8 hbbA, hbbB;
#pragma unroll
      for (int c = 0; c < 4; c++) {
        hbbA[c]     = bf16c(maskA * fast_gelu(t0A[c] + u0[c]));
        hbbA[c + 4] = bf16c(maskA * fast_gelu(t1A[c] + u1[c]));
        hbbB[c]     = bf16c(maskB * fast_gelu(t0B[c] + u0[c]));
        hbbB[c + 4] = bf16c(maskB * fast_gelu(t1B[c] + u1[c]));
      }
      {
        const short* Bp = P.B1;
        __builtin_amdgcn_s_setprio(1);
#pragma unroll
        for (int tt = 0; tt < 8; tt++) {
          short8 f0 = FRAG(Bp, 2 * tt), f1 = FRAG(Bp, 2 * tt + 1);
          rA0[tt] = MF(f0, hbbA, rA0[tt]); rB0[tt] = MF(f0, hbbB, rB0[tt]);
          rA1[tt] = MF(f1, hbbA, rA1[tt]); rB1[tt] = MF(f1, hbbB, rB1[tt]);
        }
        __builtin_amdgcn_s_setprio(0);
      }
    }
    // ---- FFN bias residual ----
#pragma unroll
    for (int kc = 0; kc < 8; kc++) {
      f32x4 b0 = *(const f32x4*)&P_bf2[32 * kc + 4 * g];
      f32x4 b1 = *(const f32x4*)&P_bf2[32 * kc + 16 + 4 * g];
#pragma unroll
      for (int c = 0; c < 4; c++) {
        rA0[kc][c] += maskA * b0[c]; rA1[kc][c] += maskA * b1[c];
        rB0[kc][c] += maskB * b0[c]; rB1[kc][c] += maskB * b1[c];
      }
    }

    // ---- candidate combine ----
    if (sidx == 0) {
      float wa = probsv[pA * 3 + 0], wb = probsv[pB * 3 + 0];
      float* oa = outp + baseA + n * 256;
      float* ob2 = outp + baseB + n * 256;
#pragma unroll
      for (int kc = 0; kc < 8; kc++) {
        f32x4 xa0, xa1, xb0, xb1;
#pragma unroll
        for (int c = 0; c < 4; c++) {
          xa0[c] = wa * rA0[kc][c]; xa1[c] = wa * rA1[kc][c];
          xb0[c] = wb * rB0[kc][c]; xb1[c] = wb * rB1[kc][c];
        }
        *(f32x4*)(oa + 32 * kc + 4 * g) = xa0;
        *(f32x4*)(oa + 32 * kc + 16 + 4 * g) = xa1;
        *(f32x4*)(ob2 + 32 * kc + 4 * g) = xb0;
        *(f32x4*)(ob2 + 32 * kc + 16 + 4 * g) = xb1;
      }
    } else if (sidx == 1 || sidx == 3) {
      int ci = (sidx == 1) ? 1 : 2;
      float wa = probsv[pA * 3 + ci], wb = probsv[pB * 3 + ci];
      float* oa = outp + baseA + n * 256;
      float* ob2 = outp + baseB + n * 256;
#pragma unroll
      for (int kc = 0; kc < 8; kc++) {
        f32x4 xa0 = *(f32x4*)(oa + 32 * kc + 4 * g);
        f32x4 xa1 = *(f32x4*)(oa + 32 * kc + 16 + 4 * g);
        f32x4 xb0 = *(f32x4*)(ob2 + 32 * kc + 4 * g);
        f32x4 xb1 = *(f32x4*)(ob2 + 32 * kc + 16 + 4 * g);
#pragma unroll
        for (int c = 0; c < 4; c++) {
          xa0[c] += wa * rA0[kc][c]; xa1[c] += wa * rA1[kc][c];
          xb0[c] += wb * rB0[kc][c]; xb1[c] += wb * rB1[kc][c];
        }
        *(f32x4*)(oa + 32 * kc + 4 * g) = xa0;
        *(f32x4*)(oa + 32 * kc + 16 + 4 * g) = xa1;
        *(f32x4*)(ob2 + 32 * kc + 4 * g) = xb0;
        *(f32x4*)(ob2 + 32 * kc + 16 + 4 * g) = xb1;
      }
    }
  }
}

__global__ void finalize_kernel(const float* __restrict__ accum, float* __restrict__ dst) {
  const float inv = 1.f / 4096.f;
  float m0 = accum[0] * inv, m1 = accum[1] * inv, m2 = accum[2] * inv;
  const float u = 1.f / 3.f;
  float d0 = m0 - u, d1 = m1 - u, d2 = m2 - u;
  dst[0] = (d0 * d0 + d1 * d1 + d2 * d2) * (1.f / 3.f);
  dst[1] = accum[3] * inv;
}

extern "C" void kernel_launch(void* const* d_in, const int* in_sizes, int n_in,
                              void* d_out, int out_size, void* d_ws, size_t ws_size,
                              hipStream_t stream) {
  const float* s    = (const float*)d_in[0];
  const float* r    = (const float*)d_in[1];
  const float* Wd1  = (const float*)d_in[2];
  const float* bd1  = (const float*)d_in[3];
  const float* Wd2  = (const float*)d_in[4];
  const float* bd2  = (const float*)d_in[5];
  const float* Wa1  = (const float*)d_in[6];
  const float* ba1  = (const float*)d_in[7];
  const float* Wa2  = (const float*)d_in[8];
  const float* ba2  = (const float*)d_in[9];
  const float* Wsp  = (const float*)d_in[10];
  const float* ln1s = (const float*)d_in[11];
  const float* ln1b = (const float*)d_in[12];
  const float* Wq   = (const float*)d_in[13];
  const float* Wk   = (const float*)d_in[14];
  const float* Wv   = (const float*)d_in[15];
  const float* Wo   = (const float*)d_in[16];
  const float* ln2s = (const float*)d_in[17];
  const float* ln2b = (const float*)d_in[18];
  const float* Wf1  = (const float*)d_in[19];
  const float* bf1  = (const float*)d_in[20];
  const float* Wf2  = (const float*)d_in[21];
  const float* bf2  = (const float*)d_in[22];

  float* out = (float*)d_out;
  float* wsf = (float*)d_ws;
  float* mask   = wsf;
  float* sproj  = wsf + 65536;
  float* probsv = wsf + 65536 + 4096;
  float* accum  = wsf + 65536 + 4096 + 12288;
  short* pk     = (short*)(wsf + 131072);
  short* Wstream = pk;             // 786432 shorts (1536 x 1KB frags)
  short* PWa1    = pk + 786432;    // 32768
  short* PWd1    = pk + 819200;    // 131072

  pack_stream<<<384, 256, 0, stream>>>(Wq, Wk, Wv, Wo, Wf1, Wf2, Wstream);
  pack_weight<<<16, 256, 0, stream>>>(Wa1, PWa1, 256, 128);
  pack_weight<<<64, 256, 0, stream>>>(Wd1, PWd1, 1024, 128);

  init_accum_kernel<<<1, 64, 0, stream>>>(accum);
  sproj_kernel<<<NPOS, 256, 0, stream>>>(s, Wsp, sproj);
  difficulty_mfma<<<64, 256, 0, stream>>>(s, PWd1, bd1, Wd2, bd2, probsv, accum);
  slot_mask_mfma<<<NPOS / 4, 256, 0, stream>>>(r, PWa1, ba1, Wa2, ba2, sproj, mask);

  reason_all<<<NPOS / 8, 256, 0, stream>>>(r, mask, probsv, out, Wstream,
                                           ln1s, ln1b, ln2s, ln2b, bf1, bf2);

  finalize_kernel<<<1, 1, 0, stream>>>(accum, out + R_ELEMS);
}